// Round 1
// baseline (383.547 us; speedup 1.0000x reference)
//
#include <hip/hip_runtime.h>
#include <hip/hip_bf16.h>

// Problem constants (match reference)
#define B_  32
#define P_  16
#define S_  256
#define D_  256
#define NG_ 128
#define N_  (B_ * NG_)     // 4096 nodes
#define E_  65536
#define H_  256

// ---------------------------------------------------------------------------
// 1) node_x[n,d] = mean_p emb[b, p, gid[b,g], d]   (n = b*NG+g)
//    Skips computing means for unused (b,s) pairs: reads 64 MB instead of 128.
// ---------------------------------------------------------------------------
__global__ __launch_bounds__(256) void k_node_mean(
    const float* __restrict__ emb, const int* __restrict__ gids,
    float* __restrict__ node_x) {
  const int n = blockIdx.x;            // 0..4095
  const int b = n >> 7;                // /NG
  const int g = n & (NG_ - 1);
  const int s = gids[b * NG_ + g];     // < S by construction
  const int d = threadIdx.x;
  const float* base = emb + (size_t)b * (P_ * S_ * D_) + (size_t)s * D_ + d;
  float acc = 0.f;
#pragma unroll
  for (int p = 0; p < P_; ++p) acc += base[(size_t)p * (S_ * D_)];
  node_x[(size_t)n * D_ + d] = acc * (1.0f / P_);
}

// ---------------------------------------------------------------------------
// 2) degree (with self-loop) and dis = rsqrt(deg)
// ---------------------------------------------------------------------------
__global__ void k_deg_init(float* __restrict__ deg) {
  int i = blockIdx.x * blockDim.x + threadIdx.x;
  if (i < N_) deg[i] = 1.0f;           // self-loop
}

__global__ void k_deg_accum(const int* __restrict__ dst, float* __restrict__ deg) {
  int e = blockIdx.x * blockDim.x + threadIdx.x;
  if (e < E_) atomicAdd(&deg[dst[e]], 1.0f);
}

__global__ void k_rsqrt(const float* __restrict__ deg, float* __restrict__ dis) {
  int i = blockIdx.x * blockDim.x + threadIdx.x;
  if (i < N_) dis[i] = rsqrtf(deg[i]);
}

// ---------------------------------------------------------------------------
// 3) GEMM h = act(x) @ W     (M=4096, K=256, Ncols=256, fp32 vector ALU)
//    16 rows per block; x rows staged in LDS (broadcast reads), W coalesced.
// ---------------------------------------------------------------------------
#define RPB 16
__global__ __launch_bounds__(256) void k_gemm(
    const float* __restrict__ x, const float* __restrict__ W,
    float* __restrict__ out, int apply_relu) {
  __shared__ float xs[RPB][D_];
  const int tid = threadIdx.x;
  const int row0 = blockIdx.x * RPB;
#pragma unroll
  for (int r = 0; r < RPB; ++r) {
    float v = x[(size_t)(row0 + r) * D_ + tid];
    xs[r][tid] = apply_relu ? fmaxf(v, 0.f) : v;
  }
  __syncthreads();
  float acc[RPB];
#pragma unroll
  for (int r = 0; r < RPB; ++r) acc[r] = 0.f;
  for (int k = 0; k < D_; k += 4) {
    float4 w;
    w.x = W[(size_t)(k + 0) * H_ + tid];
    w.y = W[(size_t)(k + 1) * H_ + tid];
    w.z = W[(size_t)(k + 2) * H_ + tid];
    w.w = W[(size_t)(k + 3) * H_ + tid];
#pragma unroll
    for (int r = 0; r < RPB; ++r) {
      float4 xv = *(const float4*)&xs[r][k];
      acc[r] = fmaf(xv.x, w.x, fmaf(xv.y, w.y, fmaf(xv.z, w.z, fmaf(xv.w, w.w, acc[r]))));
    }
  }
#pragma unroll
  for (int r = 0; r < RPB; ++r) out[(size_t)(row0 + r) * H_ + tid] = acc[r];
}

// ---------------------------------------------------------------------------
// 4) Aggregation init: out[v,h] = bias[h] + dis[v]^2 * hmat[v,h]  (self-loop)
// ---------------------------------------------------------------------------
__global__ __launch_bounds__(256) void k_agg_init(
    const float* __restrict__ hmat, const float* __restrict__ bias,
    const float* __restrict__ dis, float* __restrict__ out) {
  const int v = blockIdx.x;
  const int t = threadIdx.x;
  const float dv = dis[v];
  out[(size_t)v * H_ + t] = bias[t] + dv * dv * hmat[(size_t)v * H_ + t];
}

// ---------------------------------------------------------------------------
// 5) Edge aggregation: out[dst,h] += dis[src]*dis[dst] * hmat[src,h]
// ---------------------------------------------------------------------------
#define EPB 16
__global__ __launch_bounds__(256) void k_agg_edges(
    const float* __restrict__ hmat, const int* __restrict__ src,
    const int* __restrict__ dst, const float* __restrict__ dis,
    float* __restrict__ out) {
  const int t = threadIdx.x;
  const int e0 = blockIdx.x * EPB;
#pragma unroll
  for (int i = 0; i < EPB; ++i) {
    const int e = e0 + i;
    const int s = src[e];
    const int d = dst[e];
    const float nrm = dis[s] * dis[d];
    atomicAdd(&out[(size_t)d * H_ + t], nrm * hmat[(size_t)s * H_ + t]);
  }
}

// ---------------------------------------------------------------------------
// 6) Global mean pool: out[b,h] = mean_g x2[b*NG+g, h]
// ---------------------------------------------------------------------------
__global__ __launch_bounds__(256) void k_pool(
    const float* __restrict__ x2, float* __restrict__ out) {
  const int b = blockIdx.x;
  const int t = threadIdx.x;
  float acc = 0.f;
  for (int g = 0; g < NG_; ++g) acc += x2[(size_t)((b << 7) + g) * H_ + t];
  out[(size_t)b * H_ + t] = acc * (1.0f / NG_);
}

extern "C" void kernel_launch(void* const* d_in, const int* in_sizes, int n_in,
                              void* d_out, int out_size, void* d_ws, size_t ws_size,
                              hipStream_t stream) {
  const float* emb  = (const float*)d_in[0];   // [B,P,S,D]
  const int*   gids = (const int*)d_in[1];     // [B,NG]
  const int*   eidx = (const int*)d_in[2];     // [2,E]
  const float* W1   = (const float*)d_in[3];
  const float* b1   = (const float*)d_in[4];
  const float* W2   = (const float*)d_in[5];
  const float* b2   = (const float*)d_in[6];
  float* out = (float*)d_out;

  const int* src = eidx;        // edge_index[0]
  const int* dst = eidx + E_;   // edge_index[1]

  // Workspace layout (floats)
  float* ws = (float*)d_ws;
  float* node_x = ws;                       // 4 MB  (N*D)
  float* hbuf   = ws + (size_t)N_ * D_;     // 4 MB  (N*H)
  float* x1     = hbuf + (size_t)N_ * H_;   // 4 MB
  float* x2     = x1 + (size_t)N_ * H_;     // 4 MB
  float* dis    = x2 + (size_t)N_ * H_;     // 16 KB
  float* deg    = dis + N_;                 // 16 KB

  // 1) node features (mean over pathways for gathered substructures)
  k_node_mean<<<N_, 256, 0, stream>>>(emb, gids, node_x);

  // 2) degrees / norms
  k_deg_init<<<(N_ + 255) / 256, 256, 0, stream>>>(deg);
  k_deg_accum<<<(E_ + 255) / 256, 256, 0, stream>>>(dst, deg);
  k_rsqrt<<<(N_ + 255) / 256, 256, 0, stream>>>(deg, dis);

  // 3) layer 1: h = node_x @ W1 ; x1 = segsum(norm*h) + b1 ; relu fused into GEMM2 load
  k_gemm<<<N_ / RPB, 256, 0, stream>>>(node_x, W1, hbuf, 0);
  k_agg_init<<<N_, 256, 0, stream>>>(hbuf, b1, dis, x1);
  k_agg_edges<<<E_ / EPB, 256, 0, stream>>>(hbuf, src, dst, dis, x1);

  // 4) layer 2: h = relu(x1) @ W2 ; x2 = segsum(norm*h) + b2
  k_gemm<<<N_ / RPB, 256, 0, stream>>>(x1, W2, hbuf, 1);
  k_agg_init<<<N_, 256, 0, stream>>>(hbuf, b2, dis, x2);
  k_agg_edges<<<E_ / EPB, 256, 0, stream>>>(hbuf, src, dst, dis, x2);

  // 5) pool
  k_pool<<<B_, 256, 0, stream>>>(x2, out);
}